// Round 4
// baseline (55912.506 us; speedup 1.0000x reference)
//
#include <hip/hip_runtime.h>

// FPS: 2 batches x 131072 pts, 4096 samples/batch, seed = point 0.
// Persistent kernel, register-resident coords+dists.
//
// Evidence r0-r3: sc0 (L2-scope) polling NEVER resolves cross-block
// stores (dur tracks the sys-poll period: 1/1->11.0ms, 1/4->10.6ms,
// 1/32->23.2ms). => blocks of a batch are NOT co-located on one XCD
// under the blockIdx%8 bet; pollers' L2s serve stale clean lines which
// remote sc1 stores never invalidate. Cross-XCD rendezvous = sys scope,
// ~2.2us/step floor.
//
// This round: RUNTIME placement discovery + verified regrouping.
//  Phase 1 (sys scope, placement-agnostic): all 256 blocks publish
//    HW_REG_XCC_ID to map[blockIdx]; all poll the full map (stable once
//    written); each block LOCALLY+IDENTICALLY computes: two XCDs with
//    >=32 blocks -> batch 0/1; rank = #same-XCD blocks with lower
//    blockIdx; rank>=32 or other-XCD blocks exit. If no two such XCDs:
//    fallback grouping by blockIdx (0..63), sys sync.
//  Phase 2 (bounded, can't hang): per batch, rank0 sc0-stores a token;
//    all 32 blocks sc0-poll it with a 20000-iter cap; verdicts exchanged
//    at sys scope (unbounded-safe: every block publishes after a bounded
//    probe). Unanimous pass -> FAST: ring sync entirely sc0 (same
//    physical L2, storer and pollers share it -> coherent by
//    construction). Any failure -> sys-scope ring sync (proven r0
//    protocol). Correctness never depends on dispatch mapping (G16).
//
// Per step: fused dist-update + thread argmax -> DPP tournament (u64
// key) to lane63 + readlane broadcast -> LDS 4-way block reduce (ONE
// barrier) -> rank-slot store {key|coords} as two self-validating 16B
// quads (no ack wait) -> all waves poll (lane<32: quad0 of slot lane;
// lane>=32: quad1) -> 5-level DPP reduce over lanes 0..31 -> winner
// coords via readlane. Key = dist<<32 | s<<17 | (0x1FFFF-idx): u64 max
// == (dist desc, idx asc) == jnp.argmax tiebreak. Exact fp32.
//
// Ring safety (RING=4): a block stores step s+1 only after ALL its waves
// passed the step-s poll (the one barrier gates the storer on every
// sibling wave); a block storing s+4 (first slot reuse) must have passed
// polls s+1..s+3, which require every block's store of s+3, which
// requires those blocks passed poll s+2 and hence finished polling s.
// Argument uses poll passes only, not store acks. Zeroed slots never
// tag-match (s in 1..4095).

#define NB    32      // blocks per batch
#define TPB   256     // 4 waves
#define PPT   16      // 32*256*16 = 131072
#define NPB   131072
#define MSAMP 4096
#define RING  4

typedef unsigned long long u64;
typedef unsigned int u32;
typedef __attribute__((ext_vector_type(4))) u32 u32x4;

// ---- scoped memory ops ------------------------------------------------
__device__ __forceinline__ u32x4 ld16_l2(const u32* p) {
  u32x4 r;
  asm volatile("global_load_dwordx4 %0, %1, off sc0\n\t"
               "s_waitcnt vmcnt(0)" : "=v"(r) : "v"(p) : "memory");
  return r;
}
__device__ __forceinline__ u32x4 ld16_sys(const u32* p) {
  u32x4 r;
  asm volatile("global_load_dwordx4 %0, %1, off sc0 sc1\n\t"
               "s_waitcnt vmcnt(0)" : "=v"(r) : "v"(p) : "memory");
  return r;
}
__device__ __forceinline__ void st16_l2(u32* p, u32x4 v) {
  asm volatile("global_store_dwordx4 %0, %1, off sc0"
               :: "v"(p), "v"(v) : "memory");
}
__device__ __forceinline__ void st16_sys(u32* p, u32x4 v) {
  asm volatile("global_store_dwordx4 %0, %1, off sc0 sc1"
               :: "v"(p), "v"(v) : "memory");
}
__device__ __forceinline__ u32 ld32_l2(const u32* p) {
  u32 r;
  asm volatile("global_load_dword %0, %1, off sc0\n\t"
               "s_waitcnt vmcnt(0)" : "=v"(r) : "v"(p) : "memory");
  return r;
}
__device__ __forceinline__ u32 ld32_sys(const u32* p) {
  u32 r;
  asm volatile("global_load_dword %0, %1, off sc0 sc1\n\t"
               "s_waitcnt vmcnt(0)" : "=v"(r) : "v"(p) : "memory");
  return r;
}
__device__ __forceinline__ void st32_l2(u32* p, u32 v) {
  asm volatile("global_store_dword %0, %1, off sc0\n\t"
               "s_waitcnt vmcnt(0)" :: "v"(p), "v"(v) : "memory");
}
__device__ __forceinline__ void st32_sys(u32* p, u32 v) {
  asm volatile("global_store_dword %0, %1, off sc0 sc1\n\t"
               "s_waitcnt vmcnt(0)" :: "v"(p), "v"(v) : "memory");
}

// ---- DPP helpers ------------------------------------------------------
template<int CTRL>
__device__ __forceinline__ u64 dpp_move64(u64 x) {
  int lo = (int)(u32)(x & 0xFFFFFFFFull);
  int hi = (int)(u32)(x >> 32);
  int nlo = __builtin_amdgcn_update_dpp(lo, lo, CTRL, 0xF, 0xF, false);
  int nhi = __builtin_amdgcn_update_dpp(hi, hi, CTRL, 0xF, 0xF, false);
  return ((u64)(u32)nhi << 32) | (u64)(u32)nlo;
}
#define DPP_ROW_SHR(n)  (0x110 + (n))
#define DPP_BCAST15     0x142
#define DPP_BCAST31     0x143

__device__ __forceinline__ u64 dpp_max64_to63(u64 k) {
  u64 t;
  t = dpp_move64<DPP_ROW_SHR(1)>(k); if (t > k) k = t;
  t = dpp_move64<DPP_ROW_SHR(2)>(k); if (t > k) k = t;
  t = dpp_move64<DPP_ROW_SHR(4)>(k); if (t > k) k = t;
  t = dpp_move64<DPP_ROW_SHR(8)>(k); if (t > k) k = t;
  t = dpp_move64<DPP_BCAST15>(k);    if (t > k) k = t;
  t = dpp_move64<DPP_BCAST31>(k);    if (t > k) k = t;
  return k;                                   // lane63 = wave max
}
__device__ __forceinline__ u64 dpp_max64_to31(u64 k) {
  u64 t;
  t = dpp_move64<DPP_ROW_SHR(1)>(k); if (t > k) k = t;
  t = dpp_move64<DPP_ROW_SHR(2)>(k); if (t > k) k = t;
  t = dpp_move64<DPP_ROW_SHR(4)>(k); if (t > k) k = t;
  t = dpp_move64<DPP_ROW_SHR(8)>(k); if (t > k) k = t;
  t = dpp_move64<DPP_BCAST15>(k);    if (t > k) k = t;
  return k;                                   // lane31 = max(lanes 0..31)
}
__device__ __forceinline__ u64 bcast_key(u64 k, int srclane) {
  u32 lo = (u32)__builtin_amdgcn_readlane((int)(u32)(k & 0xFFFFFFFFull), srclane);
  u32 hi = (u32)__builtin_amdgcn_readlane((int)(u32)(k >> 32), srclane);
  return ((u64)hi << 32) | (u64)lo;
}
__device__ __forceinline__ float bcast_f32(float v, int srclane) {
  return __uint_as_float((u32)__builtin_amdgcn_readlane((int)__float_as_uint(v), srclane));
}

// ---- main FPS loop, sync scope templated ------------------------------
template<bool FAST>
__device__ __forceinline__ void fps_run(
    const float4* __restrict__ bpts, float* __restrict__ out,
    u32* __restrict__ bslots, int batch, int rank, int tid,
    u64* s_key, float* s_cx, float* s_cy, float* s_cz)
{
#pragma clang fp contract(off)
  const int lane = tid & 63;
  const int wv   = tid >> 6;
  const int base = rank * (TPB * PPT);

  float px[PPT], py[PPT], pz[PPT], dist[PPT];
#pragma unroll
  for (int k = 0; k < PPT; ++k) {
    float4 p = bpts[base + k * TPB + tid];   // row = (b, x, y, z)
    px[k] = p.y; py[k] = p.z; pz[k] = p.w;
    dist[k] = __builtin_inff();              // min(inf, d) == d bit-exactly
  }

  float4 seed = bpts[0];
  float sx = seed.y, sy = seed.z, sz = seed.w;
  if (rank == 0 && wv == 0 && lane == 0) {
    float4 o; o.x = (float)batch; o.y = sx; o.z = sy; o.w = sz;
    *(float4*)(out + (size_t)batch * MSAMP * 4) = o;
  }

  for (int s = 1; s < MSAMP; ++s) {
    // ---- fused dist update + per-thread argmax, coords tracked ----
    float bestd = -1.0f, bx = 0.f, by = 0.f, bz = 0.f; int besti = 0;
#pragma unroll
    for (int k = 0; k < PPT; ++k) {
      float dx = px[k] - sx, dy = py[k] - sy, dz = pz[k] - sz;
      float d2 = __fadd_rn(__fadd_rn(__fmul_rn(dx, dx), __fmul_rn(dy, dy)),
                           __fmul_rn(dz, dz));
      float nd = fminf(dist[k], d2);
      dist[k] = nd;
      if (nd > bestd) {                      // strict '>': first-index tiebreak
        bestd = nd; besti = base + k * TPB + tid;
        bx = px[k]; by = py[k]; bz = pz[k];
      }
    }

    u64 pv0 = ((u64)__float_as_uint(bestd) << 32) | ((u64)s << 17) |
              (u64)(0x1FFFF - besti);

    // ---- wave argmax: DPP tournament to lane63, readlane broadcast ----
    u64 kw = bcast_key(dpp_max64_to63(pv0), 63);
    int wl = __ffsll(__ballot(pv0 == kw)) - 1;   // unique: idx embedded
    float wx = bcast_f32(bx, wl), wy = bcast_f32(by, wl), wz = bcast_f32(bz, wl);
    if (lane == 0) { s_key[wv] = kw; s_cx[wv] = wx; s_cy[wv] = wy; s_cz[wv] = wz; }
    __syncthreads();                         // the ONE barrier per step

    u32* ring = bslots + (size_t)(s & (RING - 1)) * (NB * 8);
    if (wv == 0 && lane < 2) {
      u64 k0 = s_key[0], k1 = s_key[1], k2 = s_key[2], k3 = s_key[3];
      int bi = 0; u64 bk = k0;
      if (k1 > bk) { bk = k1; bi = 1; }
      if (k2 > bk) { bk = k2; bi = 2; }
      if (k3 > bk) { bk = k3; bi = 3; }
      u32x4 q;
      if (lane == 0) {                       // quad0: key + x,y (tag in key)
        q.x = (u32)(bk & 0xFFFFFFFFull); q.y = (u32)(bk >> 32);
        q.z = __float_as_uint(s_cx[bi]);  q.w = __float_as_uint(s_cy[bi]);
      } else {                               // quad1: tag + z
        q.x = (u32)s; q.y = __float_as_uint(s_cz[bi]); q.z = 0u; q.w = 0u;
      }
      u32* sp = ring + rank * 8 + lane * 4;
      if (FAST) st16_l2(sp, q); else st16_sys(sp, q);   // no ack wait
    }

    // ---- poll: lane<32 -> quad0 of slot lane; lane>=32 -> quad1 ----
    const u32* pp = ring + ((lane < 32) ? (lane * 8) : ((lane - 32) * 8 + 4));
    u32x4 q;
    for (u32 it = 0; ; ++it) {
      if (FAST) q = ((it & 255u) == 255u) ? ld16_sys(pp) : ld16_l2(pp);
      else      q = ld16_sys(pp);
      bool okp = (lane < 32) ? ((q.x >> 17) == (u32)s) : (q.x == (u32)s);
      if (__ballot(okp) == ~0ull) break;
      if (!FAST || it >= 4) __builtin_amdgcn_s_sleep(1);
    }

    // ---- cross-block argmax: 5-level DPP over lanes 0..31 ----
    u64 key = (lane < 32) ? (((u64)q.y << 32) | (u64)q.x) : 0ull;
    u64 w = bcast_key(dpp_max64_to31(key), 31);
    int wl2 = __ffsll(__ballot(key == w && lane < 32)) - 1;
    sx = bcast_f32(__uint_as_float(q.z), wl2);        // x from quad0 lane
    sy = bcast_f32(__uint_as_float(q.w), wl2);        // y from quad0 lane
    sz = bcast_f32(__uint_as_float(q.y), wl2 + 32);   // z from quad1 lane

    if (rank == 0 && wv == 0 && lane == 0) {
      float4 o; o.x = (float)batch; o.y = sx; o.z = sy; o.w = sz;
      *(float4*)(out + (size_t)(batch * MSAMP + s) * 4) = o;
    }
  }
}

__global__ __launch_bounds__(TPB, 1)
void fps_kernel(const float4* __restrict__ pts, float* __restrict__ out,
                u32* __restrict__ slots)
{
  const int tid  = threadIdx.x;
  const int lane = tid & 63;

  __shared__ u64   s_key[4];
  __shared__ float s_cx[4], s_cy[4], s_cz[4];

  u32* map   = slots + 2 * RING * NB * 8;   // 256 u32: xcc | 0x100 per block
  u32* verd  = map + 256;                   // 64 u32: per-batch verdicts
  u32* pcell = verd + 64;                   // 2 x 4 u32 probe cells (16B ea)

  // ---- phase 1: publish + poll full placement map (sys scope) ----
  u32 xcc;
  asm volatile("s_getreg_b32 %0, hwreg(HW_REG_XCC_ID)" : "=s"(xcc));
  xcc &= 0xFFu;
  if (tid == 0) st32_sys(map + blockIdx.x, xcc | 0x100u);

  const u32* mp = map + lane * 4;           // lane L holds entries 4L..4L+3
  u32x4 m;
  for (;;) {
    m = ld16_sys(mp);
    bool ok = (m.x & 0x100u) && (m.y & 0x100u) && (m.z & 0x100u) && (m.w & 0x100u);
    if (__ballot(ok) == ~0ull) break;
    __builtin_amdgcn_s_sleep(1);
  }
  u32 e0 = m.x & 0xFFu, e1 = m.y & 0xFFu, e2 = m.z & 0xFFu, e3 = m.w & 0xFFu;

  // counts per XCD (uniform: every wave sees the whole stable map)
  int cnt[8];
#pragma unroll
  for (int x = 0; x < 8; ++x)
    cnt[x] = __popcll(__ballot(e0 == (u32)x)) + __popcll(__ballot(e1 == (u32)x))
           + __popcll(__ballot(e2 == (u32)x)) + __popcll(__ballot(e3 == (u32)x));
  int c0 = -1, c1 = -1;
#pragma unroll
  for (int x = 0; x < 8; ++x)
    if (cnt[x] >= 32) { if (c0 < 0) c0 = x; else if (c1 < 0) c1 = x; }

  int batch, rank; bool fast = false;
  if (c1 >= 0) {
    const int myx = (int)xcc;
    if      (myx == c0) batch = 0;
    else if (myx == c1) batch = 1;
    else return;                            // surplus XCDs exit
    // rank = #same-XCD blocks with lower blockIdx (stable map -> unique)
    {
      const int bi = (int)blockIdx.x;
      rank  = __popcll(__ballot(e0 == (u32)myx && (lane * 4 + 0) < bi));
      rank += __popcll(__ballot(e1 == (u32)myx && (lane * 4 + 1) < bi));
      rank += __popcll(__ballot(e2 == (u32)myx && (lane * 4 + 2) < bi));
      rank += __popcll(__ballot(e3 == (u32)myx && (lane * 4 + 3) < bi));
    }
    if (rank >= 32) return;                 // surplus blocks on chosen XCD

    // ---- phase 2: BOUNDED same-L2 coherence probe + verdict ----
    u32* pc = pcell + batch * 4;
    if (rank == 0 && tid == 0) st32_l2(pc, 0xC0FFEEu);
    bool ok = false;
    for (int it = 0; it < 20000; ++it) {
      if (ld32_l2(pc) == 0xC0FFEEu) { ok = true; break; }
      if ((it & 7) == 7) __builtin_amdgcn_s_sleep(1);
    }
    if (tid == 0) st32_sys(verd + batch * 32 + rank, ok ? 0x101u : 0x102u);
    const u32* vp = verd + batch * 32;
    u32 v;
    for (;;) {
      v = (lane < 32) ? ld32_sys(vp + lane) : 0x101u;
      if (__ballot((v & 0x100u) != 0u) == ~0ull) break;
      __builtin_amdgcn_s_sleep(1);
    }
    fast = (__ballot(v == 0x101u) == ~0ull);   // unanimous pass only
  } else {
    // placement not 32-groupable: fallback grouping by blockIdx, sys sync
    if (blockIdx.x >= 64) return;
    batch = (int)(blockIdx.x >> 5);
    rank  = (int)(blockIdx.x & 31);
    fast  = false;
  }

  const float4* bpts = pts + (size_t)batch * NPB;
  u32* bslots = slots + (size_t)batch * (RING * NB * 8);

  if (fast)
    fps_run<true >(bpts, out, bslots, batch, rank, tid, s_key, s_cx, s_cy, s_cz);
  else
    fps_run<false>(bpts, out, bslots, batch, rank, tid, s_key, s_cx, s_cy, s_cz);
}

extern "C" void kernel_launch(void* const* d_in, const int* in_sizes, int n_in,
                              void* d_out, int out_size, void* d_ws, size_t ws_size,
                              hipStream_t stream) {
  const float4* pts = (const float4*)d_in[0];
  float* out = (float*)d_out;
  u32* slots = (u32*)d_ws;

  // Zero rings (8KB) + map (1KB) + verdicts (256B) + probe cells (32B):
  // stale tags/sentinels can never validate.
  hipMemsetAsync(d_ws, 0,
                 (size_t)2 * RING * NB * 32 + 256 * 4 + 64 * 4 + 8 * 4,
                 stream);

  dim3 grid(256), block(TPB);
  hipLaunchKernelGGL(fps_kernel, grid, block, 0, stream, pts, out, slots);
}

// Round 5
// 6951.099 us; speedup vs baseline: 8.0437x; 8.0437x over previous
//
#include <hip/hip_runtime.h>

// FPS: 2 batches x 131072 pts, 4096 samples/batch, seed = point 0.
// EXACT certified K-lookahead FPS (K=8): amortize one device-scope
// rendezvous over up to 8 committed FPS steps.
//
// Evidence r0-r4: sc0-scope polls NEVER observe remote-CU stores on this
// part (dur tracks sys-poll period 1/1->11.0ms, 1/4->10.6ms, 1/32->23.2,
// 1/256->~170ms; XCC_ID grouping + passed same-L2 probe didn't help).
// Device-scope rendezvous RT ~2.2us is irreducible => reduce rendezvous
// COUNT, not latency. All placement/scope games removed.
//
// Per rendezvous r (all 32 blocks of a batch):
//  1. EXTRACT: block's exact top-8 candidates by key (8 rounds of
//     block-argmax + winner-thread rescan with a 16-bit removal mask).
//     Key = dist_bits<<32 | r<<17 | (0x1FFFF - idx): u64 order ==
//     (dist desc, idx asc) == jnp.argmax first-index tiebreak.
//  2. SHIP: 16 self-validating 16B quads/block (key+xy | tag+z),
//     r2's proven sync: dual-scope store (sc0 then sc0 sc1, same bytes,
//     no ack wait) + poll sc0 with sc1 every 4th iter + s_sleep backoff.
//     Each wave polls its own 128 of the 512 quads; __syncthreads joins.
//  3. SIM (identical on every block; candidates are identical bytes =>
//     deterministic): thread t owns candidate (block t>>3, rank t&7).
//     Step 1 always exact (global max = some block's top-1, in pool).
//     Step t>=2 committed iff sim-winner dist STRICTLY > cutoff
//     (= max over blocks of 8th-best shipped dist): any unshipped point
//     has score <= its orig dist <= cutoff < winner => exact, tiebreak
//     included. Else stop: commit j>=1 steps (progress guaranteed).
//  4. COMMIT: rank0 writes rows S+1..S+j; every block min-updates its
//     4096 register-resident dists vs the j winners (same fp sequence
//     as reference, ascending order => bit-exact).
//
// Ring safety (RING=4, over rendezvous rounds): a block stores round r+1
// only after ALL its waves passed the round-r poll (the post-poll
// __syncthreads gates the storer); storing r+4 (slot reuse) requires
// passing polls r+1..r+3 which require every block's store of r+3 which
// requires those blocks long finished polling r. Tags: quad0 keylo>>17
// == r, quad1 word0 == r; stale round r-4 or zeroed slots never match
// (r in 1..4094, 15-bit field).

#define NB    32      // blocks per batch
#define TPB   256     // 4 waves
#define PPT   16      // 32*256*16 = 131072
#define NPB   131072
#define MSAMP 4096
#define RING  4
#define KLOOK 8       // candidates per block / max committed steps
#define QPB   (2*KLOOK)        // 16 quads per block per round
#define RB_U32 (NB*QPB*4)      // 2048 u32 = 8KB per ring slot

typedef unsigned long long u64;
typedef unsigned int u32;
typedef __attribute__((ext_vector_type(4))) u32 u32x4;

// ---- scoped memory ops (r2's proven set) ------------------------------
__device__ __forceinline__ u32x4 ld16_l2(const u32* p) {
  u32x4 r;
  asm volatile("global_load_dwordx4 %0, %1, off sc0\n\t"
               "s_waitcnt vmcnt(0)" : "=v"(r) : "v"(p) : "memory");
  return r;
}
__device__ __forceinline__ u32x4 ld16_sys(const u32* p) {
  u32x4 r;
  asm volatile("global_load_dwordx4 %0, %1, off sc0 sc1\n\t"
               "s_waitcnt vmcnt(0)" : "=v"(r) : "v"(p) : "memory");
  return r;
}
__device__ __forceinline__ void st16_dual(u32* p, u32x4 v) {
  asm volatile("global_store_dwordx4 %0, %1, off sc0\n\t"
               "global_store_dwordx4 %0, %1, off sc0 sc1"
               :: "v"(p), "v"(v) : "memory");
}

// ---- DPP helpers ------------------------------------------------------
template<int CTRL>
__device__ __forceinline__ u64 dpp_move64(u64 x) {
  int lo = (int)(u32)(x & 0xFFFFFFFFull);
  int hi = (int)(u32)(x >> 32);
  int nlo = __builtin_amdgcn_update_dpp(lo, lo, CTRL, 0xF, 0xF, false);
  int nhi = __builtin_amdgcn_update_dpp(hi, hi, CTRL, 0xF, 0xF, false);
  return ((u64)(u32)nhi << 32) | (u64)(u32)nlo;
}
#define DPP_ROW_SHR(n)  (0x110 + (n))
#define DPP_BCAST15     0x142
#define DPP_BCAST31     0x143

__device__ __forceinline__ u64 dpp_max64_to63(u64 k) {
  u64 t;
  t = dpp_move64<DPP_ROW_SHR(1)>(k); if (t > k) k = t;
  t = dpp_move64<DPP_ROW_SHR(2)>(k); if (t > k) k = t;
  t = dpp_move64<DPP_ROW_SHR(4)>(k); if (t > k) k = t;
  t = dpp_move64<DPP_ROW_SHR(8)>(k); if (t > k) k = t;
  t = dpp_move64<DPP_BCAST15>(k);    if (t > k) k = t;
  t = dpp_move64<DPP_BCAST31>(k);    if (t > k) k = t;
  return k;                                   // lane63 = wave max
}
__device__ __forceinline__ u64 bcast_key(u64 k, int srclane) {
  u32 lo = (u32)__builtin_amdgcn_readlane((int)(u32)(k & 0xFFFFFFFFull), srclane);
  u32 hi = (u32)__builtin_amdgcn_readlane((int)(u32)(k >> 32), srclane);
  return ((u64)hi << 32) | (u64)lo;
}
__device__ __forceinline__ float bcast_f32(float v, int srclane) {
  return __uint_as_float((u32)__builtin_amdgcn_readlane((int)__float_as_uint(v), srclane));
}

struct BMax { u64 k; float x, y, z; };

// Block-wide argmax over per-thread (key, xyz). ONE barrier inside.
// sb = alternating LDS slot base (0/4) to avoid WAR across uses.
__device__ __forceinline__ BMax block_max(u64 tk, float tx, float ty, float tz,
    int lane, int wv, int sb,
    u64* s_key, float* s_cx, float* s_cy, float* s_cz) {
  u64 wk = bcast_key(dpp_max64_to63(tk), 63);
  int wl = __ffsll(__ballot(tk == wk)) - 1;     // keys unique (idx embedded)
  float wx = bcast_f32(tx, wl), wy = bcast_f32(ty, wl), wz = bcast_f32(tz, wl);
  if (lane == 0) { s_key[sb+wv]=wk; s_cx[sb+wv]=wx; s_cy[sb+wv]=wy; s_cz[sb+wv]=wz; }
  __syncthreads();
  u64 k0=s_key[sb],k1=s_key[sb+1],k2=s_key[sb+2],k3=s_key[sb+3];
  int bi=sb; u64 bk=k0;
  if (k1>bk){bk=k1;bi=sb+1;}
  if (k2>bk){bk=k2;bi=sb+2;}
  if (k3>bk){bk=k3;bi=sb+3;}
  BMax r; r.k=bk; r.x=s_cx[bi]; r.y=s_cy[bi]; r.z=s_cz[bi];
  return r;
}

__global__ __launch_bounds__(TPB, 1)
void fps_kernel(const float4* __restrict__ pts, float* __restrict__ out,
                u32* __restrict__ slots)
{
#pragma clang fp contract(off)
  const int batch = blockIdx.x >> 5;
  const int rank  = blockIdx.x & (NB - 1);
  const int tid   = threadIdx.x;
  const int lane  = tid & 63;
  const int wv    = tid >> 6;

  __shared__ u64   s_key[8];
  __shared__ float s_cx[8], s_cy[8], s_cz[8];
  __shared__ u32   s_extk[KLOOK * 2];
  __shared__ float s_extc[KLOOK * 3];
  __shared__ float s_win[KLOOK][3];
  __shared__ u32   s_quads[NB * QPB * 4];     // 8 KB candidate mirror

  const float4* bpts = pts + (size_t)batch * NPB;
  u32* bslots = slots + (size_t)batch * (RING * RB_U32);
  const int base = rank * (TPB * PPT);

  float px[PPT], py[PPT], pz[PPT], dist[PPT];
  float4 seed = bpts[0];
  const float sx = seed.y, sy = seed.z, sz = seed.w;
#pragma unroll
  for (int k = 0; k < PPT; ++k) {
    float4 p = bpts[base + k * TPB + tid];     // row = (b, x, y, z)
    px[k] = p.y; py[k] = p.z; pz[k] = p.w;
    float dx = px[k]-sx, dy = py[k]-sy, dz = pz[k]-sz;
    dist[k] = __fadd_rn(__fadd_rn(__fmul_rn(dx,dx), __fmul_rn(dy,dy)),
                        __fmul_rn(dz,dz));     // == reference dist init
  }
  if (rank == 0 && tid == 0) {
    float4 o; o.x=(float)batch; o.y=sx; o.z=sy; o.w=sz;
    *(float4*)(out + (size_t)batch * MSAMP * 4) = o;
  }

  int S = 0;            // committed samples beyond the seed (rows 1..4095)
  u32 r = 0;            // rendezvous round
  int sb = 0;           // LDS parity for block_max

  while (S < MSAMP - 1) {
    r += 1;
    const int jmax = (KLOOK < (MSAMP-1) - S) ? KLOOK : ((MSAMP-1) - S);

    // ---- 1. extraction: exact block top-8 ----
    u32 mask = 0;
    u64 tk = 0; float tx=0.f, ty=0.f, tz=0.f; int tbk = 0;
#pragma unroll
    for (int k = 0; k < PPT; ++k) {
      u64 kk = ((u64)__float_as_uint(dist[k]) << 32) | ((u64)r << 17) |
               (u64)(0x1FFFF - (base + k * TPB + tid));
      if (kk > tk) { tk = kk; tx = px[k]; ty = py[k]; tz = pz[k]; tbk = k; }
    }
    for (int c = 0; c < KLOOK; ++c) {
      BMax w = block_max(tk, tx, ty, tz, lane, wv, sb, s_key, s_cx, s_cy, s_cz);
      sb ^= 4;
      if (tid == 0) {
        s_extk[c*2]   = (u32)(w.k & 0xFFFFFFFFull);
        s_extk[c*2+1] = (u32)(w.k >> 32);
        s_extc[c*3+0] = w.x; s_extc[c*3+1] = w.y; s_extc[c*3+2] = w.z;
      }
      if (tk == w.k) {                         // my point won: mask + rescan
        mask |= 1u << tbk;
        tk = 0; tx = ty = tz = 0.f; tbk = 0;
#pragma unroll
        for (int k = 0; k < PPT; ++k) {
          if (!((mask >> k) & 1u)) {
            u64 kk = ((u64)__float_as_uint(dist[k]) << 32) | ((u64)r << 17) |
                     (u64)(0x1FFFF - (base + k * TPB + tid));
            if (kk > tk) { tk = kk; tx = px[k]; ty = py[k]; tz = pz[k]; tbk = k; }
          }
        }
      }
    }
    __syncthreads();                           // s_ext visible to storers

    // ---- 2. ship + poll (r2's proven protocol) ----
    u32* ring = bslots + (size_t)(r & (RING - 1)) * RB_U32;
    if (wv == 0 && lane < QPB) {
      int c = lane >> 1, h = lane & 1;
      u32x4 q;
      if (h == 0) { q.x = s_extk[c*2]; q.y = s_extk[c*2+1];
                    q.z = __float_as_uint(s_extc[c*3+0]);
                    q.w = __float_as_uint(s_extc[c*3+1]); }
      else        { q.x = r; q.y = __float_as_uint(s_extc[c*3+2]);
                    q.z = 0u; q.w = 0u; }
      st16_dual(ring + rank * (QPB*4) + lane * 4, q);
    }

    const int g0 = wv * 128 + lane;            // wave polls its 128 quads
    const u32* p0 = ring + g0 * 4;
    const u32* p1 = ring + (g0 + 64) * 4;
    const int h = lane & 1;                    // both my quads same parity
    u32x4 qa, qb;
    for (u32 it = 0; ; ++it) {
      if ((it & 3u) == 3u) { qa = ld16_sys(p0); qb = ld16_sys(p1); }
      else                 { qa = ld16_l2 (p0); qb = ld16_l2 (p1); }
      bool ok = (h == 0) ? (((qa.x >> 17) == r) && ((qb.x >> 17) == r))
                         : ((qa.x == r) && (qb.x == r));
      if (__ballot(ok) == ~0ull) break;
      if (it >= 1) __builtin_amdgcn_s_sleep(1);
    }
    *(u32x4*)&s_quads[g0 * 4]        = qa;
    *(u32x4*)&s_quads[(g0 + 64) * 4] = qb;
    __syncthreads();                           // all 512 quads in LDS

    // ---- 3. sim: thread t owns candidate (block t>>3, c = t&7) ----
    const int qb0 = ((tid >> 3) * QPB + (tid & 7) * 2) * 4;
    u64 ck = ((u64)s_quads[qb0+1] << 32) | (u64)s_quads[qb0];
    float cx = __uint_as_float(s_quads[qb0+2]);
    float cy = __uint_as_float(s_quads[qb0+3]);
    float cz = __uint_as_float(s_quads[qb0+5]);

    // cutoff = max over blocks of 8th-best shipped key (dist field)
    BMax cw = block_max(((tid & 7) == 7) ? ck : 0ull, 0.f, 0.f, 0.f,
                        lane, wv, sb, s_key, s_cx, s_cy, s_cz);
    sb ^= 4;
    const u32 cutd = (u32)(cw.k >> 32);

    int j = 0;
    for (int t = 0; t < jmax; ++t) {
      BMax w = block_max(ck, cx, cy, cz, lane, wv, sb, s_key, s_cx, s_cy, s_cz);
      sb ^= 4;
      if (t > 0 && (u32)(w.k >> 32) <= cutd) break;   // not certified: stop
      if (tid == 0) { s_win[t][0]=w.x; s_win[t][1]=w.y; s_win[t][2]=w.z; }
      j = t + 1;
      // exact candidate score update (same fp sequence as main update)
      float dx = cx - w.x, dy = cy - w.y, dz = cz - w.z;
      float d2 = __fadd_rn(__fadd_rn(__fmul_rn(dx,dx), __fmul_rn(dy,dy)),
                           __fmul_rn(dz,dz));
      float nd = fminf(__uint_as_float((u32)(ck >> 32)), d2);
      ck = ((u64)__float_as_uint(nd) << 32) | (ck & 0xFFFFFFFFull);
    }
    __syncthreads();                           // s_win visible

    // ---- 4. commit: output rows + batched dist update ----
    if (rank == 0 && tid < j) {
      float4 o; o.x = (float)batch;
      o.y = s_win[tid][0]; o.z = s_win[tid][1]; o.w = s_win[tid][2];
      *(float4*)(out + (size_t)(batch * MSAMP + S + 1 + tid) * 4) = o;
    }
    for (int i = 0; i < j; ++i) {              // ascending = reference order
      const float wx = s_win[i][0], wy = s_win[i][1], wz = s_win[i][2];
#pragma unroll
      for (int k = 0; k < PPT; ++k) {
        float dx = px[k]-wx, dy = py[k]-wy, dz = pz[k]-wz;
        float d2 = __fadd_rn(__fadd_rn(__fmul_rn(dx,dx), __fmul_rn(dy,dy)),
                             __fmul_rn(dz,dz));
        dist[k] = fminf(dist[k], d2);
      }
    }
    S += j;
  }
}

extern "C" void kernel_launch(void* const* d_in, const int* in_sizes, int n_in,
                              void* d_out, int out_size, void* d_ws, size_t ws_size,
                              hipStream_t stream) {
  const float4* pts = (const float4*)d_in[0];
  float* out = (float*)d_out;
  u32* slots = (u32*)d_ws;

  // Zero both batches' rings (64 KB): stale tags can never validate.
  hipMemsetAsync(d_ws, 0, (size_t)2 * RING * RB_U32 * 4, stream);

  dim3 grid(2 * NB), block(TPB);
  hipLaunchKernelGGL(fps_kernel, grid, block, 0, stream, pts, out, slots);
}

// Round 6
// 3667.554 us; speedup vs baseline: 15.2452x; 1.8953x over previous
//
#include <hip/hip_runtime.h>

// FPS: 2 batches x 131072 pts, 4096 samples/batch, seed = point 0.
// EXACT certified lookahead FPS, v2: wave-level candidate shipping,
// pruned barrier-free in-register sim, JCAP=64 commits per rendezvous.
//
// Evidence r0-r5: sys-scope rendezvous RT ~2.2-3us is the floor (sc0
// never resolves cross-CU on this part); r5 (block top-8 lookahead)
// proved certification works (6951us, absmax 0) but spent ~18 barriers
// + LDS round-trips per rendezvous and certified only ~3-4 steps.
//
// This round:
//  * EXTRACT per WAVE (no barriers): wave's exact top-8 by key via 8
//    DPP-tournament rounds + winner-lane rescan (removal mask). Lanes
//    2c/2c+1 capture round-c winner into a ship quad; lanes 0..15 store
//    16B each (sys scope, unacked) as soon as the wave finishes.
//  * CUTOFF = max over all 128 waves of wave-8th-best key. Every wave-8th
//    <= its block-8th => cutoff is LOWER than r5's => MORE certified
//    steps. Any unshipped point of wave w has key <= wave-w-8th <= cutoff.
//  * POLL: each wave polls its 512-quad quarter with ONE 8-load asm
//    batch per lane (single vmcnt), sys scope, s_sleep backoff; mirrors
//    to LDS; __syncthreads => block sees all 2048 quads.
//  * PRUNE: only candidates with key > cutoff can ever be certified;
//    compact them to s_pool (LDS atomic). m ~ 100-400 expected.
//  * SIM (exact, identical on all waves, NO barriers): per-lane NC =
//    1/2/4/8 candidates (m<=64/128/256/512), per step: lane max -> DPP
//    max -> readlane coords; commit t=0 always (global max is in pool
//    and > cutoff), t>=1 iff winner dist STRICTLY > cutoff dist; lane t
//    stashes winner t. Candidate scores updated with the reference fp
//    sequence => bit-exact. m>512 falls back to LDS block_max sim (4
//    cands/thread, exact, rare).
//  * COMMIT: wave0 of rank0 writes rows S+1..S+j from lane stashes;
//    all threads min-update their 16 register dists per winner in
//    ascending order (reference order => bit-exact).
//
// Key = dist_bits<<32 | r<<17 | (0x1FFFF - idx): u64 order ==
// (dist desc, idx asc) == jnp.argmax first-index tiebreak (r < 2^15).
//
// Ring safety (RING=2, induction over rendezvous rounds): wave stores
// round r+2 only after its block's mirror barrier of round r+1, which
// requires all 4 waves' quarter-polls of r+1, which require ALL 128
// wave-slots stored r+1, which requires every block passed its mirror
// barrier of round r => everyone finished polling round r before any
// slot of round r is overwritten. Tags embed full r; zeroed slots and
// stale r-2 data never match (r >= 1).

#define NB    32
#define TPB   256
#define PPT   16
#define NPB   131072
#define MSAMP 4096
#define RING  2
#define KW    8                 // candidates per wave
#define NWAVE 128               // waves per batch
#define NQUAD (NWAVE * 16)      // 2048 quads per round per batch
#define RB_U32 (NQUAD * 4)      // 8192 u32 = 32KB per ring slot
#define NCAND (NWAVE * KW)      // 1024
#define JCAP  64

typedef unsigned long long u64;
typedef unsigned int u32;
typedef __attribute__((ext_vector_type(4))) u32 u32x4;

__device__ __forceinline__ void st16_sys(u32* p, u32x4 v) {
  asm volatile("global_store_dwordx4 %0, %1, off sc0 sc1"
               :: "v"(p), "v"(v) : "memory");
}
// 8 poll loads issued back-to-back, ONE vmcnt drain (single RT).
__device__ __forceinline__ void ld16x8_sys(
    const u32* p0, const u32* p1, const u32* p2, const u32* p3,
    const u32* p4, const u32* p5, const u32* p6, const u32* p7,
    u32x4& q0, u32x4& q1, u32x4& q2, u32x4& q3,
    u32x4& q4, u32x4& q5, u32x4& q6, u32x4& q7) {
  asm volatile(
    "global_load_dwordx4 %0, %8, off sc0 sc1\n\t"
    "global_load_dwordx4 %1, %9, off sc0 sc1\n\t"
    "global_load_dwordx4 %2, %10, off sc0 sc1\n\t"
    "global_load_dwordx4 %3, %11, off sc0 sc1\n\t"
    "global_load_dwordx4 %4, %12, off sc0 sc1\n\t"
    "global_load_dwordx4 %5, %13, off sc0 sc1\n\t"
    "global_load_dwordx4 %6, %14, off sc0 sc1\n\t"
    "global_load_dwordx4 %7, %15, off sc0 sc1\n\t"
    "s_waitcnt vmcnt(0)"
    : "=v"(q0), "=v"(q1), "=v"(q2), "=v"(q3),
      "=v"(q4), "=v"(q5), "=v"(q6), "=v"(q7)
    : "v"(p0), "v"(p1), "v"(p2), "v"(p3),
      "v"(p4), "v"(p5), "v"(p6), "v"(p7)
    : "memory");
}

// ---- DPP helpers (proven r2-r5) ---------------------------------------
template<int CTRL>
__device__ __forceinline__ u64 dpp_move64(u64 x) {
  int lo = (int)(u32)(x & 0xFFFFFFFFull);
  int hi = (int)(u32)(x >> 32);
  int nlo = __builtin_amdgcn_update_dpp(lo, lo, CTRL, 0xF, 0xF, false);
  int nhi = __builtin_amdgcn_update_dpp(hi, hi, CTRL, 0xF, 0xF, false);
  return ((u64)(u32)nhi << 32) | (u64)(u32)nlo;
}
#define DPP_ROW_SHR(n)  (0x110 + (n))
#define DPP_BCAST15     0x142
#define DPP_BCAST31     0x143

__device__ __forceinline__ u64 dpp_max64_to63(u64 k) {
  u64 t;
  t = dpp_move64<DPP_ROW_SHR(1)>(k); if (t > k) k = t;
  t = dpp_move64<DPP_ROW_SHR(2)>(k); if (t > k) k = t;
  t = dpp_move64<DPP_ROW_SHR(4)>(k); if (t > k) k = t;
  t = dpp_move64<DPP_ROW_SHR(8)>(k); if (t > k) k = t;
  t = dpp_move64<DPP_BCAST15>(k);    if (t > k) k = t;
  t = dpp_move64<DPP_BCAST31>(k);    if (t > k) k = t;
  return k;                                   // lane63 = wave max
}
__device__ __forceinline__ u64 bcast_key(u64 k, int srclane) {
  u32 lo = (u32)__builtin_amdgcn_readlane((int)(u32)(k & 0xFFFFFFFFull), srclane);
  u32 hi = (u32)__builtin_amdgcn_readlane((int)(u32)(k >> 32), srclane);
  return ((u64)hi << 32) | (u64)lo;
}
__device__ __forceinline__ float bcast_f32(float v, int srclane) {
  return __uint_as_float((u32)__builtin_amdgcn_readlane((int)__float_as_uint(v), srclane));
}

struct BMax { u64 k; float x, y, z; };
__device__ __forceinline__ BMax block_max(u64 tk, float tx, float ty, float tz,
    int lane, int wv, int sb,
    u64* s_key, float* s_cx, float* s_cy, float* s_cz) {
  u64 wk = bcast_key(dpp_max64_to63(tk), 63);
  int wl = __ffsll(__ballot(tk == wk)) - 1;
  float wx = bcast_f32(tx, wl), wy = bcast_f32(ty, wl), wz = bcast_f32(tz, wl);
  if (lane == 0) { s_key[sb+wv]=wk; s_cx[sb+wv]=wx; s_cy[sb+wv]=wy; s_cz[sb+wv]=wz; }
  __syncthreads();
  u64 k0=s_key[sb],k1=s_key[sb+1],k2=s_key[sb+2],k3=s_key[sb+3];
  int bi=sb; u64 bk=k0;
  if (k1>bk){bk=k1;bi=sb+1;}
  if (k2>bk){bk=k2;bi=sb+2;}
  if (k3>bk){bk=k3;bi=sb+3;}
  BMax r; r.k=bk; r.x=s_cx[bi]; r.y=s_cy[bi]; r.z=s_cz[bi];
  return r;
}

// ---- pruned in-register sim, NO barriers, identical on all waves ------
template<int NC>
__device__ __forceinline__ int sim_wave(const u32* s_pool, int m, u32 cutd,
    int jmax, int lane, float& ox, float& oy, float& oz) {
#pragma clang fp contract(off)
  u64 ck[NC]; float cx[NC], cy[NC], cz[NC];
#pragma unroll
  for (int i = 0; i < NC; ++i) {
    int idx = lane + i * 64;
    if (idx < m) {
      const u32* b = s_pool + idx * 5;
      ck[i] = ((u64)b[1] << 32) | (u64)b[0];
      cx[i] = __uint_as_float(b[2]); cy[i] = __uint_as_float(b[3]);
      cz[i] = __uint_as_float(b[4]);
    } else { ck[i] = 0; cx[i] = cy[i] = cz[i] = 0.f; }
  }
  int j = 0;
  for (int t = 0; t < jmax; ++t) {
    u64 tk = ck[0]; float mx = cx[0], my = cy[0], mz = cz[0];
#pragma unroll
    for (int i = 1; i < NC; ++i)
      if (ck[i] > tk) { tk = ck[i]; mx = cx[i]; my = cy[i]; mz = cz[i]; }
    u64 wk = bcast_key(dpp_max64_to63(tk), 63);
    if (t > 0 && (u32)(wk >> 32) <= cutd) break;   // not certified: stop
    int wl = __ffsll(__ballot(tk == wk)) - 1;
    float wx = bcast_f32(mx, wl), wy = bcast_f32(my, wl), wz = bcast_f32(mz, wl);
    if (lane == t) { ox = wx; oy = wy; oz = wz; }  // stash winner t
    j = t + 1;
#pragma unroll
    for (int i = 0; i < NC; ++i) {
      float dx = cx[i]-wx, dy = cy[i]-wy, dz = cz[i]-wz;
      float d2 = __fadd_rn(__fadd_rn(__fmul_rn(dx,dx), __fmul_rn(dy,dy)),
                           __fmul_rn(dz,dz));
      float nd = fminf(__uint_as_float((u32)(ck[i] >> 32)), d2);
      ck[i] = ((u64)__float_as_uint(nd) << 32) | (ck[i] & 0xFFFFFFFFull);
    }
  }
  return j;
}

// ---- LDS fallback sim (m > 512; exact; rare) --------------------------
__device__ __forceinline__ int sim_block(const u32* s_pool, int m, u32 cutd,
    int jmax, int tid, int lane, int wv, int& sb,
    u64* s_key, float* s_cx, float* s_cy, float* s_cz, float (*s_win)[3]) {
#pragma clang fp contract(off)
  u64 ck[4]; float cx[4], cy[4], cz[4];
#pragma unroll
  for (int i = 0; i < 4; ++i) {
    int idx = tid + i * 256;
    if (idx < m) {
      const u32* b = s_pool + idx * 5;
      ck[i] = ((u64)b[1] << 32) | (u64)b[0];
      cx[i] = __uint_as_float(b[2]); cy[i] = __uint_as_float(b[3]);
      cz[i] = __uint_as_float(b[4]);
    } else { ck[i] = 0; cx[i] = cy[i] = cz[i] = 0.f; }
  }
  int j = 0;
  for (int t = 0; t < jmax; ++t) {
    u64 tk = ck[0]; float mx = cx[0], my = cy[0], mz = cz[0];
#pragma unroll
    for (int i = 1; i < 4; ++i)
      if (ck[i] > tk) { tk = ck[i]; mx = cx[i]; my = cy[i]; mz = cz[i]; }
    BMax w = block_max(tk, mx, my, mz, lane, wv, sb, s_key, s_cx, s_cy, s_cz);
    sb ^= 4;
    if (t > 0 && (u32)(w.k >> 32) <= cutd) break;
    if (tid == 0) { s_win[t][0]=w.x; s_win[t][1]=w.y; s_win[t][2]=w.z; }
    j = t + 1;
#pragma unroll
    for (int i = 0; i < 4; ++i) {
      float dx = cx[i]-w.x, dy = cy[i]-w.y, dz = cz[i]-w.z;
      float d2 = __fadd_rn(__fadd_rn(__fmul_rn(dx,dx), __fmul_rn(dy,dy)),
                           __fmul_rn(dz,dz));
      float nd = fminf(__uint_as_float((u32)(ck[i] >> 32)), d2);
      ck[i] = ((u64)__float_as_uint(nd) << 32) | (ck[i] & 0xFFFFFFFFull);
    }
  }
  __syncthreads();                           // s_win visible
  return j;
}

__global__ __launch_bounds__(TPB, 1)
void fps_kernel(const float4* __restrict__ pts, float* __restrict__ out,
                u32* __restrict__ slots)
{
#pragma clang fp contract(off)
  const int batch = blockIdx.x >> 5;
  const int rank  = blockIdx.x & (NB - 1);
  const int tid   = threadIdx.x;
  const int lane  = tid & 63;
  const int wv    = tid >> 6;
  const int ws_id = rank * 4 + wv;           // wave-slot 0..127

  __shared__ u32   s_quads[NWAVE * 68];      // mirror, 68-u32 padded slots
  __shared__ u32   s_pool[NCAND * 5];        // pruned candidates
  __shared__ float s_win[JCAP][3];
  __shared__ u64   s_key[8];
  __shared__ float s_cx[8], s_cy[8], s_cz[8];
  __shared__ int   s_cnt2[2];                // ping-pong compact counters

  const float4* bpts = pts + (size_t)batch * NPB;
  u32* bslots = slots + (size_t)batch * (RING * RB_U32);
  const int base = rank * (TPB * PPT);

  float px[PPT], py[PPT], pz[PPT], dist[PPT];
  float4 seed = bpts[0];
  const float sx = seed.y, sy = seed.z, sz = seed.w;
#pragma unroll
  for (int k = 0; k < PPT; ++k) {
    float4 p = bpts[base + k * TPB + tid];   // row = (b, x, y, z)
    px[k] = p.y; py[k] = p.z; pz[k] = p.w;
    float dx = px[k]-sx, dy = py[k]-sy, dz = pz[k]-sz;
    dist[k] = __fadd_rn(__fadd_rn(__fmul_rn(dx,dx), __fmul_rn(dy,dy)),
                        __fmul_rn(dz,dz));   // == reference dist init
  }
  if (rank == 0 && tid == 0) {
    float4 o; o.x=(float)batch; o.y=sx; o.z=sy; o.w=sz;
    *(float4*)(out + (size_t)batch * MSAMP * 4) = o;
  }
  if (tid == 0) { s_cnt2[0] = 0; s_cnt2[1] = 0; }
  __syncthreads();

  int S = 0; u32 r = 0; int sb = 0;

  while (S < MSAMP - 1) {
    r += 1;
    const int rem = (MSAMP - 1) - S;
    const int jmax = (rem < JCAP) ? rem : JCAP;

    // ---- EXTRACT: wave top-8, pure DPP, no barriers ----
    u32 mask = 0; u64 tk = 0; float tx=0.f, ty=0.f, tz=0.f; int tbk = 0;
#pragma unroll
    for (int k = 0; k < PPT; ++k) {
      u64 kk = ((u64)__float_as_uint(dist[k]) << 32) | ((u64)r << 17) |
               (u64)(0x1FFFF - (base + k * TPB + tid));
      if (kk > tk) { tk = kk; tx = px[k]; ty = py[k]; tz = pz[k]; tbk = k; }
    }
    u32x4 shipq;
    for (int c = 0; c < KW; ++c) {
      u64 wk = bcast_key(dpp_max64_to63(tk), 63);
      int wl = __ffsll(__ballot(tk == wk)) - 1;
      float wx = bcast_f32(tx, wl), wy = bcast_f32(ty, wl), wz = bcast_f32(tz, wl);
      if (lane == 2*c)     { shipq.x=(u32)(wk & 0xFFFFFFFFull); shipq.y=(u32)(wk>>32);
                             shipq.z=__float_as_uint(wx); shipq.w=__float_as_uint(wy); }
      if (lane == 2*c + 1) { shipq.x=r; shipq.y=__float_as_uint(wz);
                             shipq.z=0u; shipq.w=0u; }
      if (tk == wk) {                        // my point won: mask + rescan
        mask |= 1u << tbk;
        tk = 0; tx = ty = tz = 0.f; tbk = 0;
#pragma unroll
        for (int k = 0; k < PPT; ++k) {
          if (!((mask >> k) & 1u)) {
            u64 kk = ((u64)__float_as_uint(dist[k]) << 32) | ((u64)r << 17) |
                     (u64)(0x1FFFF - (base + k * TPB + tid));
            if (kk > tk) { tk = kk; tx = px[k]; ty = py[k]; tz = pz[k]; tbk = k; }
          }
        }
      }
    }

    // ---- SHIP: wave stores its 16 quads immediately ----
    u32* ring = bslots + (size_t)(r & (RING - 1)) * RB_U32;
    if (lane < 16) st16_sys(ring + (ws_id * 16 + lane) * 4, shipq);

    // ---- POLL: my wave's 512-quad quarter, 8 loads / lane, one RT ----
    const int gb = wv * 512 + lane;
    const u32 *pp0 = ring + (gb      ) * 4, *pp1 = ring + (gb +  64) * 4,
              *pp2 = ring + (gb + 128) * 4, *pp3 = ring + (gb + 192) * 4,
              *pp4 = ring + (gb + 256) * 4, *pp5 = ring + (gb + 320) * 4,
              *pp6 = ring + (gb + 384) * 4, *pp7 = ring + (gb + 448) * 4;
    u32x4 q0,q1,q2,q3,q4,q5,q6,q7;
    for (u32 it = 0; ; ++it) {
      ld16x8_sys(pp0,pp1,pp2,pp3,pp4,pp5,pp6,pp7, q0,q1,q2,q3,q4,q5,q6,q7);
      bool ok;
      if ((lane & 1) == 0)
        ok = ((q0.x>>17)==r)&&((q1.x>>17)==r)&&((q2.x>>17)==r)&&((q3.x>>17)==r)&&
             ((q4.x>>17)==r)&&((q5.x>>17)==r)&&((q6.x>>17)==r)&&((q7.x>>17)==r);
      else
        ok = (q0.x==r)&&(q1.x==r)&&(q2.x==r)&&(q3.x==r)&&
             (q4.x==r)&&(q5.x==r)&&(q6.x==r)&&(q7.x==r);
      if (__ballot(ok) == ~0ull) break;
      __builtin_amdgcn_s_sleep(1);
    }
    // reset NEXT round's compact counter (safe: ordered by mirror barriers)
    if (tid == 0) s_cnt2[(r + 1) & 1] = 0;
    // mirror my 8 quads to LDS (padded slots: 68 u32 / wave-slot)
    {
      int g = gb;
      *(u32x4*)&s_quads[(g>>4)*68 + (g&15)*4] = q0; g += 64;
      *(u32x4*)&s_quads[(g>>4)*68 + (g&15)*4] = q1; g += 64;
      *(u32x4*)&s_quads[(g>>4)*68 + (g&15)*4] = q2; g += 64;
      *(u32x4*)&s_quads[(g>>4)*68 + (g&15)*4] = q3; g += 64;
      *(u32x4*)&s_quads[(g>>4)*68 + (g&15)*4] = q4; g += 64;
      *(u32x4*)&s_quads[(g>>4)*68 + (g&15)*4] = q5; g += 64;
      *(u32x4*)&s_quads[(g>>4)*68 + (g&15)*4] = q6; g += 64;
      *(u32x4*)&s_quads[(g>>4)*68 + (g&15)*4] = q7;
    }
    __syncthreads();                         // barrier 1: all 2048 in LDS

    // ---- CUTOFF: max over 128 wave-8th keys (per wave, no barrier) ----
    u64 cutk;
    {
      int w0 = lane, w1 = lane + 64;
      u64 k0 = ((u64)s_quads[w0*68 + 57] << 32) | (u64)s_quads[w0*68 + 56];
      u64 k1 = ((u64)s_quads[w1*68 + 57] << 32) | (u64)s_quads[w1*68 + 56];
      u64 ct = (k0 > k1) ? k0 : k1;
      cutk = bcast_key(dpp_max64_to63(ct), 63);
    }
    const u32 cutd = (u32)(cutk >> 32);

    // ---- PRUNE: compact candidates with key > cutk ----
    int* cnt = &s_cnt2[r & 1];
#pragma unroll
    for (int i = 0; i < 4; ++i) {
      int cg = tid * 4 + i;
      int qb = (cg >> 3) * 68 + (cg & 7) * 8;
      u32 lo = s_quads[qb], hi = s_quads[qb + 1];
      u64 kk = ((u64)hi << 32) | (u64)lo;
      if (kk > cutk) {
        int pos = atomicAdd(cnt, 1);
        u32* d = &s_pool[pos * 5];
        d[0]=lo; d[1]=hi; d[2]=s_quads[qb+2]; d[3]=s_quads[qb+3]; d[4]=s_quads[qb+5];
      }
    }
    __syncthreads();                         // barrier 2: pool + m final
    const int m = *cnt;

    // ---- SIM ----
    float ox = 0.f, oy = 0.f, oz = 0.f;
    int j;
    if      (m <=  64) j = sim_wave<1>(s_pool, m, cutd, jmax, lane, ox, oy, oz);
    else if (m <= 128) j = sim_wave<2>(s_pool, m, cutd, jmax, lane, ox, oy, oz);
    else if (m <= 256) j = sim_wave<4>(s_pool, m, cutd, jmax, lane, ox, oy, oz);
    else if (m <= 512) j = sim_wave<8>(s_pool, m, cutd, jmax, lane, ox, oy, oz);
    else {
      j = sim_block(s_pool, m, cutd, jmax, tid, lane, wv, sb,
                    s_key, s_cx, s_cy, s_cz, s_win);
      if (lane < j) { ox = s_win[lane][0]; oy = s_win[lane][1]; oz = s_win[lane][2]; }
    }

    // ---- COMMIT: output rows + batched register dist update ----
    if (rank == 0 && wv == 0 && lane < j) {
      float4 o; o.x = (float)batch; o.y = ox; o.z = oy; o.w = oz;
      *(float4*)(out + (size_t)(batch * MSAMP + S + 1 + lane) * 4) = o;
    }
    for (int i = 0; i < j; ++i) {            // ascending = reference order
      float wx = bcast_f32(ox, i), wy = bcast_f32(oy, i), wz = bcast_f32(oz, i);
#pragma unroll
      for (int k = 0; k < PPT; ++k) {
        float dx = px[k]-wx, dy = py[k]-wy, dz = pz[k]-wz;
        float d2 = __fadd_rn(__fadd_rn(__fmul_rn(dx,dx), __fmul_rn(dy,dy)),
                             __fmul_rn(dz,dz));
        dist[k] = fminf(dist[k], d2);
      }
    }
    S += j;
  }
}

extern "C" void kernel_launch(void* const* d_in, const int* in_sizes, int n_in,
                              void* d_out, int out_size, void* d_ws, size_t ws_size,
                              hipStream_t stream) {
  const float4* pts = (const float4*)d_in[0];
  float* out = (float*)d_out;
  u32* slots = (u32*)d_ws;

  // Zero both batches' rings (128 KB): stale tags can never validate.
  hipMemsetAsync(d_ws, 0, (size_t)2 * RING * RB_U32 * 4, stream);

  dim3 grid(2 * NB), block(TPB);
  hipLaunchKernelGGL(fps_kernel, grid, block, 0, stream, pts, out, slots);
}